// Round 4
// baseline (304.225 us; speedup 1.0000x reference)
//
#include <hip/hip_runtime.h>

typedef unsigned int uint;
typedef unsigned short ushort;

typedef __bf16 bf16x8 __attribute__((ext_vector_type(8)));
typedef __bf16 bf16x2 __attribute__((ext_vector_type(2)));
typedef float f32x4 __attribute__((ext_vector_type(4)));
typedef float f32x16 __attribute__((ext_vector_type(16)));
typedef uint uint2v __attribute__((ext_vector_type(2)));

union U4 { uint4 u; bf16x8 v; };
union UB2 { bf16x2 v; uint u; };

__device__ __forceinline__ ushort f2bf(float f){
  uint u = __float_as_uint(f);
  u += 0x7fffu + ((u >> 16) & 1u);
  return (ushort)(u >> 16);
}

__device__ __forceinline__ uint packbf(float lo, float hi){
  UB2 t; t.v[0] = (__bf16)lo; t.v[1] = (__bf16)hi;   // v_cvt_pk_bf16_f32
  return t.u;
}

__device__ __forceinline__ float exp2a(float x){
  float r; asm("v_exp_f32 %0, %1" : "=v"(r) : "v"(x)); return r;
}

__device__ __forceinline__ void gload16(const void* g, void* l){
  __builtin_amdgcn_global_load_lds((const __attribute__((address_space(1))) uint*)g,
                                   (__attribute__((address_space(3))) uint*)l, 16, 0, 0);
}

__device__ __forceinline__ f32x16 mfma32(U4 a, U4 b, f32x16 c){
  return __builtin_amdgcn_mfma_f32_32x32x16_bf16(a.v, b.v, c, 0, 0, 0);
}

// ---------------------------------------------------------------------------
// GEMM: C[m,n] = sum_k A[m,k]*B[k,n] (+bias). A row-major (M x 1024) bf16,
// B transposed (Bt: N x 1024, K-contiguous) bf16. fp32 MFMA accumulation.
// Double-buffered LDS (64 KB), counted vmcnt(8) — loads span a full K-step.
// mode 0: bf16 row-major; mode 1: bf16 -> (B,H,D,T); mode 2: fp32 row-major.
// Grid (64,8); XCD-aware bijective block swizzle.
// ---------------------------------------------------------------------------
__global__ __launch_bounds__(256, 2) void gemm_bt(
    const ushort* __restrict__ Ahp, const ushort* __restrict__ Bhp,
    const float* __restrict__ bias, void* __restrict__ outp,
    int mode, float oscale)
{
  __shared__ uint4 smem4[4096];          // 64 KB: 2 x (A 16K + B 16K)
  char* sm = (char*)smem4;

  const int tid  = threadIdx.x;
  const int lane = tid & 63;
  const int wid  = tid >> 6;
  const int wm = (wid >> 1) * 64;
  const int wn = (wid & 1) * 64;

  int lin = blockIdx.y * 64 + blockIdx.x;
  int xcd = lin & 7, j = lin >> 3;
  const long tm = (long)(xcd * 8 + (j & 7)) * 128;
  const long tn = (long)(j >> 3) * 128;

  const char* gA = (const char*)Ahp;
  const char* gB = (const char*)Bhp;

  f32x4 acc[4][4] = {};

  auto stage = [&](char* buf, int ks){
    const int koff = ks * 128;
    #pragma unroll
    for (int c = 0; c < 4; c++){
      int o   = (tid + 256*c) * 16;
      int row = o >> 7;
      int src = (o & 127) ^ ((row & 7) << 4);
      gload16(gA + (tm + row)*2048 + koff + src, buf + o);
      gload16(gB + (tn + row)*2048 + koff + src, buf + 16384 + o);
    }
  };

  stage(sm, 0);
  for (int ks = 0; ks < 16; ks++){
    char* cur = sm + (ks & 1) * 32768;
    char* nxt = sm + ((ks + 1) & 1) * 32768;
    if (ks < 15){
      stage(nxt, ks + 1);
      asm volatile("s_waitcnt vmcnt(8)" ::: "memory");
    } else {
      asm volatile("s_waitcnt vmcnt(0)" ::: "memory");
    }
    __builtin_amdgcn_s_barrier();

    char* sAh = cur;
    char* sBh = cur + 16384;
    #pragma unroll
    for (int k = 0; k < 2; k++){
      const int kb = k*64 + (lane >> 4)*16;
      U4 ah[4], bh[4];
      #pragma unroll
      for (int m = 0; m < 4; m++){
        int row = wm + m*16 + (lane & 15);
        ah[m].u = *(const uint4*)(sAh + row*128 + (kb ^ ((row & 7) << 4)));
      }
      #pragma unroll
      for (int n = 0; n < 4; n++){
        int row = wn + n*16 + (lane & 15);
        bh[n].u = *(const uint4*)(sBh + row*128 + (kb ^ ((row & 7) << 4)));
      }
      __builtin_amdgcn_s_setprio(1);
      #pragma unroll
      for (int m = 0; m < 4; m++)
      #pragma unroll
      for (int n = 0; n < 4; n++)
        acc[m][n] = __builtin_amdgcn_mfma_f32_16x16x32_bf16(ah[m].v, bh[n].v, acc[m][n], 0,0,0);
      __builtin_amdgcn_s_setprio(0);
    }
    asm volatile("" ::: "memory");
    __builtin_amdgcn_s_barrier();        // cur may be overwritten next iter
  }

  // C/D layout: col = lane&15, row = (lane>>4)*4 + r
  #pragma unroll
  for (int n = 0; n < 4; n++){
    int colg = (int)tn + wn + n*16 + (lane & 15);
    float bv = bias[colg];
    #pragma unroll
    for (int m = 0; m < 4; m++){
      int rowg0 = (int)tm + wm + m*16 + ((lane >> 4) * 4);
      float v0 = (acc[m][n][0] + bv) * oscale;
      float v1 = (acc[m][n][1] + bv) * oscale;
      float v2 = (acc[m][n][2] + bv) * oscale;
      float v3 = (acc[m][n][3] + bv) * oscale;
      if (mode == 0){
        ushort* o = (ushort*)outp;
        o[(long)(rowg0+0)*1024 + colg] = f2bf(v0);
        o[(long)(rowg0+1)*1024 + colg] = f2bf(v1);
        o[(long)(rowg0+2)*1024 + colg] = f2bf(v2);
        o[(long)(rowg0+3)*1024 + colg] = f2bf(v3);
      } else if (mode == 1){
        int b = rowg0 >> 11, t0 = rowg0 & 2047;
        int h = colg >> 6, d = colg & 63;
        ushort4 o4;
        o4.x = f2bf(v0); o4.y = f2bf(v1); o4.z = f2bf(v2); o4.w = f2bf(v3);
        *(ushort4*)&((ushort*)outp)[(((long)(b*16 + h))*64 + d)*2048 + t0] = o4;
      } else {
        float* o = (float*)outp;
        o[(long)(rowg0+0)*1024 + colg] = v0;
        o[(long)(rowg0+1)*1024 + colg] = v1;
        o[(long)(rowg0+2)*1024 + colg] = v2;
        o[(long)(rowg0+3)*1024 + colg] = v3;
      }
    }
  }
}

// Build P^T B-fragments from packed words via permlane32_swap.
__device__ __forceinline__ void mkfrag(const uint (&pk)[8], U4 (&out)[2])
{
  #pragma unroll
  for (int kl = 0; kl < 2; kl++){
    int bb = kl*4;
    uint2v r02 = __builtin_amdgcn_permlane32_swap(pk[bb+0], pk[bb+2], false, false);
    uint2v r13 = __builtin_amdgcn_permlane32_swap(pk[bb+1], pk[bb+3], false, false);
    out[kl].u = make_uint4(r02[0], r13[0], r02[1], r13[1]);
  }
}

// ---------------------------------------------------------------------------
// Flash attention, no-max softmax (exp2-space, scale*log2e folded into Q).
// Q,K flat (B*T, 1024) bf16; Vt (B,H,D,T) bf16; Y flat (B*T, 1024) bf16.
// 4 waves/block, 32 q-rows/wave (128 q/block), grid 1024 -> 4 blocks/CU,
// KV chunks of 64, double-buffered staging, counted vmcnt, raw s_barrier.
// ---------------------------------------------------------------------------
__global__ __launch_bounds__(256, 4) void attn_kernel(
    const ushort* __restrict__ Qg, const ushort* __restrict__ Kg,
    const ushort* __restrict__ Vtg, ushort* __restrict__ Yg)
{
  __shared__ uint4 smem[2048];            // 32 KB: 2 x (K 8KB + V 8KB)
  char* sK0 = (char*)smem;
  char* sV0 = (char*)smem + 8192;
  char* sK1 = (char*)smem + 16384;
  char* sV1 = (char*)smem + 24576;

  const int tid  = threadIdx.x;
  const int lane = tid & 63;
  const int w    = tid >> 6;
  const int ql   = lane & 31;
  const int hh   = lane >> 5;

  // XCD swizzle: all 16 q-blocks of a head land on one XCD (K/V L2-resident).
  int lin = blockIdx.y * 16 + blockIdx.x;       // 1024 blocks
  int xcd = lin & 7, j = lin >> 3;              // j in [0,128)
  const int bh  = (j >> 4) * 8 + xcd;
  const int qb  = j & 15;
  const int tq0 = qb * 128 + w * 32;
  const int b = bh >> 4, h = bh & 15;

  // Q fragments: qf[c] = Q[tq0+ql][16c+8hh+j], flat layout
  U4 qf[4];
  const char* qrow = (const char*)Qg + (long)(b*2048 + tq0 + ql)*2048 + h*128 + hh*16;
  #pragma unroll
  for (int c = 0; c < 4; c++) qf[c].u = *(const uint4*)(qrow + c*32);

  f32x16 y0 = {}, y1 = {};
  float ls = 0.f;

  const char* kbase = (const char*)Kg  + (long)b*2048*2048 + h*128;
  const char* vbase = (const char*)Vtg + (long)bh*64*4096;

  auto stage = [&](char* dK, char* dV, int kc){
    #pragma unroll
    for (int c2 = 0; c2 < 2; c2++){
      int o   = tid*16 + c2*4096;
      int row = o >> 7;
      int src = (o & 127) ^ ((row & 7) << 4);
      gload16(kbase + (long)(kc*64 + row)*2048 + src, dK + o);
      gload16(vbase + (long)row*4096 + (long)kc*128 + src, dV + o);
    }
  };

  auto sm = [&](f32x16& s, uint (&pk)[8]){
    float ps = 0.f;
    #pragma unroll
    for (int r = 0; r < 16; r++){ s[r] = exp2a(s[r]); ps += s[r]; }
    ls += ps;
    #pragma unroll
    for (int i = 0; i < 8; i++) pk[i] = packbf(s[2*i], s[2*i+1]);
  };

  auto body = [&](int kc, char* cK, char* cV, char* nK, char* nV){
    if (kc < 31){
      stage(nK, nV, kc + 1);
      asm volatile("s_waitcnt vmcnt(4)" ::: "memory");
    } else {
      asm volatile("s_waitcnt vmcnt(0)" ::: "memory");
    }
    __builtin_amdgcn_s_barrier();

    // QK^T: S^T = mfma(K, Q^T)
    f32x16 s0 = {}, s1 = {};
    __builtin_amdgcn_s_setprio(1);
    #pragma unroll
    for (int ksd = 0; ksd < 4; ksd++){
      int kb = ksd*32 + hh*16;
      U4 a0, a1;
      { int r = ql;      a0.u = *(const uint4*)(cK + r*128 + (kb ^ ((r & 7) << 4))); }
      { int r = 32 + ql; a1.u = *(const uint4*)(cK + r*128 + (kb ^ ((r & 7) << 4))); }
      s0 = mfma32(a0, qf[ksd], s0);
      s1 = mfma32(a1, qf[ksd], s1);
    }
    __builtin_amdgcn_s_setprio(0);

    uint pk0[8], pk1[8];
    sm(s0, pk0); sm(s1, pk1);
    U4 f0[2], f1[2];
    mkfrag(pk0, f0); mkfrag(pk1, f1);

    // PV: y^T += V^T x P^T
    __builtin_amdgcn_s_setprio(1);
    #pragma unroll
    for (int n = 0; n < 2; n++){
      #pragma unroll
      for (int kl = 0; kl < 2; kl++){
        int kvo = n*64 + kl*32 + hh*16;
        U4 a0, a1;
        { int r = ql;      a0.u = *(const uint4*)(cV + r*128 + (kvo ^ ((r & 7) << 4))); }
        { int r = 32 + ql; a1.u = *(const uint4*)(cV + r*128 + (kvo ^ ((r & 7) << 4))); }
        U4 bb = n ? f1[kl] : f0[kl];
        y0 = mfma32(a0, bb, y0);
        y1 = mfma32(a1, bb, y1);
      }
    }
    __builtin_amdgcn_s_setprio(0);

    if (kc < 31){
      asm volatile("" ::: "memory");
      __builtin_amdgcn_s_barrier();
    }
  };

  stage(sK0, sV0, 0);
  for (int kc2 = 0; kc2 < 16; kc2++){
    body(2*kc2 + 0, sK0, sV0, sK1, sV1);
    body(2*kc2 + 1, sK1, sV1, sK0, sV0);
  }

  float lt  = ls + __shfl_xor(ls, 32);
  float inv = 1.0f / lt;
  int tq = tq0 + ql;
  ushort* yrow = Yg + ((long)b*2048 + tq)*1024 + h*64;
  #pragma unroll
  for (int qi = 0; qi < 4; qi++){
    ushort4 o0, o1;
    o0.x = f2bf(y0[qi*4+0]*inv); o0.y = f2bf(y0[qi*4+1]*inv);
    o0.z = f2bf(y0[qi*4+2]*inv); o0.w = f2bf(y0[qi*4+3]*inv);
    o1.x = f2bf(y1[qi*4+0]*inv); o1.y = f2bf(y1[qi*4+1]*inv);
    o1.z = f2bf(y1[qi*4+2]*inv); o1.w = f2bf(y1[qi*4+3]*inv);
    *(ushort4*)(yrow + qi*8 + hh*4)      = o0;
    *(ushort4*)(yrow + 32 + qi*8 + hh*4) = o1;
  }
}

// ---------------------------------------------------------------------------
__global__ void cast_x_kernel(const float* __restrict__ x, ushort* __restrict__ xh)
{
  int i = blockIdx.x*256 + threadIdx.x;
  float4 v = ((const float4*)x)[i];
  ushort4 h;
  h.x = f2bf(v.x); h.y = f2bf(v.y); h.z = f2bf(v.z); h.w = f2bf(v.w);
  ((ushort4*)xh)[i] = h;
}

// W (1024x1024 fp32) -> W^T bf16 (K-contiguous), 64x64 tile transpose via LDS.
__global__ void wsplit_kernel(const float* __restrict__ W, ushort* __restrict__ Th)
{
  __shared__ float tile[64][65];
  const int tid = threadIdx.x;
  const int k0 = blockIdx.x * 64;
  const int n0 = blockIdx.y * 64;
  #pragma unroll
  for (int c = 0; c < 4; c++){
    int idx = tid + 256*c;
    int r = idx >> 4, c4 = idx & 15;
    float4 v = *(const float4*)&W[(long)(k0 + r)*1024 + n0 + c4*4];
    tile[r][c4*4+0] = v.x; tile[r][c4*4+1] = v.y;
    tile[r][c4*4+2] = v.z; tile[r][c4*4+3] = v.w;
  }
  __syncthreads();
  #pragma unroll
  for (int c = 0; c < 4; c++){
    int idx = tid + 256*c;
    int nr = idx >> 4, k4 = idx & 15;
    ushort4 hh;
    hh.x = f2bf(tile[k4*4+0][nr]); hh.y = f2bf(tile[k4*4+1][nr]);
    hh.z = f2bf(tile[k4*4+2][nr]); hh.w = f2bf(tile[k4*4+3][nr]);
    *(ushort4*)&Th[(long)(n0 + nr)*1024 + k0 + k4*4] = hh;
  }
}

// ---------------------------------------------------------------------------
extern "C" void kernel_launch(void* const* d_in, const int* in_sizes, int n_in,
                              void* d_out, int out_size, void* d_ws, size_t ws_size,
                              hipStream_t stream)
{
  const float* x  = (const float*)d_in[0];
  const float* Wq = (const float*)d_in[1];
  const float* bq = (const float*)d_in[2];
  const float* Wk = (const float*)d_in[3];
  const float* bk = (const float*)d_in[4];
  const float* Wv = (const float*)d_in[5];
  const float* bv = (const float*)d_in[6];
  const float* Wp = (const float*)d_in[7];
  const float* bp = (const float*)d_in[8];

  char* ws = (char*)d_ws;
  const size_t SZ_X = 16777216; // 8192*1024*2 bytes
  const size_t SZ_W = 2097152;  // 1024*1024*2 bytes
  ushort* xh  = (ushort*)(ws);
  ushort* wqh = (ushort*)(ws + SZ_X);
  ushort* wkh = (ushort*)(ws + SZ_X + 1*SZ_W);
  ushort* wvh = (ushort*)(ws + SZ_X + 2*SZ_W);
  ushort* wph = (ushort*)(ws + SZ_X + 3*SZ_W);
  ushort* Qb  = (ushort*)(ws + SZ_X + 4*SZ_W);
  ushort* Kb  = (ushort*)(ws + 2*SZ_X + 4*SZ_W);
  ushort* Vtb = (ushort*)(ws + 3*SZ_X + 4*SZ_W);
  ushort* Yb  = (ushort*)(ws + 4*SZ_X + 4*SZ_W);

  cast_x_kernel<<<8192, 256, 0, stream>>>(x, xh);
  dim3 wg(16, 16);
  wsplit_kernel<<<wg, 256, 0, stream>>>(Wq, wqh);
  wsplit_kernel<<<wg, 256, 0, stream>>>(Wk, wkh);
  wsplit_kernel<<<wg, 256, 0, stream>>>(Wv, wvh);
  wsplit_kernel<<<wg, 256, 0, stream>>>(Wp, wph);

  dim3 gg(64, 8);
  // Q folds in softmax scale AND log2(e): 0.125 * 1.44269504
  gemm_bt<<<gg, 256, 0, stream>>>(xh, wqh, bq, Qb, 0, 0.18033688f);
  gemm_bt<<<gg, 256, 0, stream>>>(xh, wkh, bk, Kb, 0, 1.0f);
  gemm_bt<<<gg, 256, 0, stream>>>(xh, wvh, bv, Vtb, 1, 1.0f);

  dim3 ag(16, 64);
  attn_kernel<<<ag, 256, 0, stream>>>(Qb, Kb, Vtb, Yb);

  gemm_bt<<<gg, 256, 0, stream>>>(Yb, wph, bp, d_out, 2, 1.0f);
}

// Round 5
// 272.647 us; speedup vs baseline: 1.1158x; 1.1158x over previous
//
#include <hip/hip_runtime.h>

typedef unsigned int uint;
typedef unsigned short ushort;

typedef __bf16 bf16x8 __attribute__((ext_vector_type(8)));
typedef __bf16 bf16x2 __attribute__((ext_vector_type(2)));
typedef float f32x4 __attribute__((ext_vector_type(4)));
typedef float f32x16 __attribute__((ext_vector_type(16)));
typedef uint uint2v __attribute__((ext_vector_type(2)));

union U4 { uint4 u; bf16x8 v; };
union UB2 { bf16x2 v; uint u; };

__device__ __forceinline__ ushort f2bf(float f){
  uint u = __float_as_uint(f);
  u += 0x7fffu + ((u >> 16) & 1u);
  return (ushort)(u >> 16);
}

__device__ __forceinline__ uint packbf(float lo, float hi){
  UB2 t; t.v[0] = (__bf16)lo; t.v[1] = (__bf16)hi;   // v_cvt_pk_bf16_f32
  return t.u;
}

__device__ __forceinline__ float exp2a(float x){
  float r; asm("v_exp_f32 %0, %1" : "=v"(r) : "v"(x)); return r;
}

__device__ __forceinline__ void gload16(const void* g, void* l){
  __builtin_amdgcn_global_load_lds((const __attribute__((address_space(1))) uint*)g,
                                   (__attribute__((address_space(3))) uint*)l, 16, 0, 0);
}

__device__ __forceinline__ f32x16 mfma32(U4 a, U4 b, f32x16 c){
  return __builtin_amdgcn_mfma_f32_32x32x16_bf16(a.v, b.v, c, 0, 0, 0);
}

// ---------------------------------------------------------------------------
// Fused Q/K/V projection GEMM. A = xh (8192 x 1024 bf16 row-major),
// Wt = 3 contiguous transposed weights (3 x 1024 x 1024 bf16, K-contiguous).
// Grid (64,24) = 1536 blocks -> 3 blocks/CU (launch_bounds cap 170 VGPR).
// XCD mapping: each XCD owns 8 m-blocks (A panel 2MB L2-resident); within an
// XCD, m varies fastest so B panels get 8x L2 reuse.
// w=0 -> Qb (bf16 flat, scaled), w=1 -> Kb (bf16 flat), w=2 -> Vt (B,H,D,T).
// ---------------------------------------------------------------------------
__global__ __launch_bounds__(256, 3) void gemm_qkv(
    const ushort* __restrict__ xh, const ushort* __restrict__ wbase,
    const float* __restrict__ bq, const float* __restrict__ bk,
    const float* __restrict__ bv,
    ushort* __restrict__ Qb, ushort* __restrict__ Kb, ushort* __restrict__ Vtb,
    float qscale)
{
  __shared__ uint4 smem4[2048];          // 32 KB: A 16K + B 16K
  char* sAh = (char*)smem4;
  char* sBh = (char*)smem4 + 16384;

  const int tid  = threadIdx.x;
  const int lane = tid & 63;
  const int wid  = tid >> 6;
  const int wm = (wid >> 1) * 64;
  const int wn = (wid & 1) * 64;

  int hwlin = blockIdx.y * 64 + blockIdx.x;
  int xcd = hwlin & 7, io = hwlin >> 3;        // io in [0,192)
  int mb  = xcd * 8 + (io & 7);                // m-block in [0,64)
  int nv  = io >> 3;                           // [0,24)
  int nb  = nv & 7;                            // n-block in [0,8)
  int w   = nv >> 3;                           // 0=Q 1=K 2=V
  const long tm = (long)mb * 128;
  const long tn = (long)nb * 128;

  const char* gA = (const char*)xh;
  const char* gB = (const char*)(wbase + (long)w * 1048576);

  f32x4 acc[4][4] = {};

  for (int ks = 0; ks < 8; ks++){
    const int koff = ks * 128;
    #pragma unroll
    for (int c = 0; c < 4; c++){
      int o   = (tid + 256*c) * 16;
      int row = o >> 7;
      int src = (o & 127) ^ ((row & 7) << 4);
      gload16(gA + (tm + row)*2048 + koff + src, sAh + o);
      gload16(gB + (tn + row)*2048 + koff + src, sBh + o);
    }
    __syncthreads();
    #pragma unroll
    for (int k = 0; k < 2; k++){
      const int kb = k*64 + (lane >> 4)*16;
      U4 ah[4], bh[4];
      #pragma unroll
      for (int m = 0; m < 4; m++){
        int row = wm + m*16 + (lane & 15);
        ah[m].u = *(const uint4*)(sAh + row*128 + (kb ^ ((row & 7) << 4)));
      }
      #pragma unroll
      for (int n = 0; n < 4; n++){
        int row = wn + n*16 + (lane & 15);
        bh[n].u = *(const uint4*)(sBh + row*128 + (kb ^ ((row & 7) << 4)));
      }
      __builtin_amdgcn_s_setprio(1);
      #pragma unroll
      for (int m = 0; m < 4; m++)
      #pragma unroll
      for (int n = 0; n < 4; n++)
        acc[m][n] = __builtin_amdgcn_mfma_f32_16x16x32_bf16(ah[m].v, bh[n].v, acc[m][n], 0,0,0);
      __builtin_amdgcn_s_setprio(0);
    }
    __syncthreads();
  }
  // second half of K (identical; split to keep loop body small)
  for (int ks = 8; ks < 16; ks++){
    const int koff = ks * 128;
    #pragma unroll
    for (int c = 0; c < 4; c++){
      int o   = (tid + 256*c) * 16;
      int row = o >> 7;
      int src = (o & 127) ^ ((row & 7) << 4);
      gload16(gA + (tm + row)*2048 + koff + src, sAh + o);
      gload16(gB + (tn + row)*2048 + koff + src, sBh + o);
    }
    __syncthreads();
    #pragma unroll
    for (int k = 0; k < 2; k++){
      const int kb = k*64 + (lane >> 4)*16;
      U4 ah[4], bh[4];
      #pragma unroll
      for (int m = 0; m < 4; m++){
        int row = wm + m*16 + (lane & 15);
        ah[m].u = *(const uint4*)(sAh + row*128 + (kb ^ ((row & 7) << 4)));
      }
      #pragma unroll
      for (int n = 0; n < 4; n++){
        int row = wn + n*16 + (lane & 15);
        bh[n].u = *(const uint4*)(sBh + row*128 + (kb ^ ((row & 7) << 4)));
      }
      __builtin_amdgcn_s_setprio(1);
      #pragma unroll
      for (int m = 0; m < 4; m++)
      #pragma unroll
      for (int n = 0; n < 4; n++)
        acc[m][n] = __builtin_amdgcn_mfma_f32_16x16x32_bf16(ah[m].v, bh[n].v, acc[m][n], 0,0,0);
      __builtin_amdgcn_s_setprio(0);
    }
    __syncthreads();
  }

  const float* bias = (w == 0) ? bq : (w == 1) ? bk : bv;
  const float oscale = (w == 0) ? qscale : 1.0f;

  // C/D layout: col = lane&15, row = (lane>>4)*4 + r
  #pragma unroll
  for (int n = 0; n < 4; n++){
    int colg = (int)tn + wn + n*16 + (lane & 15);
    float bv_ = bias[colg];
    #pragma unroll
    for (int m = 0; m < 4; m++){
      int rowg0 = (int)tm + wm + m*16 + ((lane >> 4) * 4);
      float v0 = (acc[m][n][0] + bv_) * oscale;
      float v1 = (acc[m][n][1] + bv_) * oscale;
      float v2 = (acc[m][n][2] + bv_) * oscale;
      float v3 = (acc[m][n][3] + bv_) * oscale;
      if (w < 2){
        ushort* o = (w == 0) ? Qb : Kb;
        o[(long)(rowg0+0)*1024 + colg] = f2bf(v0);
        o[(long)(rowg0+1)*1024 + colg] = f2bf(v1);
        o[(long)(rowg0+2)*1024 + colg] = f2bf(v2);
        o[(long)(rowg0+3)*1024 + colg] = f2bf(v3);
      } else {
        int b = rowg0 >> 11, t0 = rowg0 & 2047;
        int h = colg >> 6, d = colg & 63;
        ushort4 o4;
        o4.x = f2bf(v0); o4.y = f2bf(v1); o4.z = f2bf(v2); o4.w = f2bf(v3);
        *(ushort4*)&Vtb[(((long)(b*16 + h))*64 + d)*2048 + t0] = o4;
      }
    }
  }
}

// ---------------------------------------------------------------------------
// Output projection GEMM (fp32 out). A = Yb (8192 x 1024 bf16), B = Wp^T.
// Grid (64,8); XCD-aware bijective swizzle. (R3-proven kernel, mode-2 only.)
// ---------------------------------------------------------------------------
__global__ __launch_bounds__(256, 2) void gemm_out(
    const ushort* __restrict__ Ahp, const ushort* __restrict__ Bhp,
    const float* __restrict__ bias, float* __restrict__ outp)
{
  __shared__ uint4 smem4[2048];          // 32 KB
  char* sAh = (char*)smem4;
  char* sBh = (char*)smem4 + 16384;

  const int tid  = threadIdx.x;
  const int lane = tid & 63;
  const int wid  = tid >> 6;
  const int wm = (wid >> 1) * 64;
  const int wn = (wid & 1) * 64;

  int lin = blockIdx.y * 64 + blockIdx.x;
  int xcd = lin & 7, j = lin >> 3;
  const long tm = (long)(xcd * 8 + (j & 7)) * 128;
  const long tn = (long)(j >> 3) * 128;

  const char* gA = (const char*)Ahp;
  const char* gB = (const char*)Bhp;

  f32x4 acc[4][4] = {};

  for (int ks = 0; ks < 16; ks++){
    const int koff = ks * 128;
    #pragma unroll
    for (int c = 0; c < 4; c++){
      int o   = (tid + 256*c) * 16;
      int row = o >> 7;
      int src = (o & 127) ^ ((row & 7) << 4);
      gload16(gA + (tm + row)*2048 + koff + src, sAh + o);
      gload16(gB + (tn + row)*2048 + koff + src, sBh + o);
    }
    __syncthreads();
    #pragma unroll
    for (int k = 0; k < 2; k++){
      const int kb = k*64 + (lane >> 4)*16;
      U4 ah[4], bh[4];
      #pragma unroll
      for (int m = 0; m < 4; m++){
        int row = wm + m*16 + (lane & 15);
        ah[m].u = *(const uint4*)(sAh + row*128 + (kb ^ ((row & 7) << 4)));
      }
      #pragma unroll
      for (int n = 0; n < 4; n++){
        int row = wn + n*16 + (lane & 15);
        bh[n].u = *(const uint4*)(sBh + row*128 + (kb ^ ((row & 7) << 4)));
      }
      __builtin_amdgcn_s_setprio(1);
      #pragma unroll
      for (int m = 0; m < 4; m++)
      #pragma unroll
      for (int n = 0; n < 4; n++)
        acc[m][n] = __builtin_amdgcn_mfma_f32_16x16x32_bf16(ah[m].v, bh[n].v, acc[m][n], 0,0,0);
      __builtin_amdgcn_s_setprio(0);
    }
    __syncthreads();
  }

  #pragma unroll
  for (int n = 0; n < 4; n++){
    int colg = (int)tn + wn + n*16 + (lane & 15);
    float bv_ = bias[colg];
    #pragma unroll
    for (int m = 0; m < 4; m++){
      int rowg0 = (int)tm + wm + m*16 + ((lane >> 4) * 4);
      #pragma unroll
      for (int r = 0; r < 4; r++)
        outp[(long)(rowg0+r)*1024 + colg] = acc[m][n][r] + bv_;
    }
  }
}

// Build P^T B-fragments from packed words via permlane32_swap.
__device__ __forceinline__ void mkfrag(const uint (&pk)[8], U4 (&out)[2])
{
  #pragma unroll
  for (int kl = 0; kl < 2; kl++){
    int bb = kl*4;
    uint2v r02 = __builtin_amdgcn_permlane32_swap(pk[bb+0], pk[bb+2], false, false);
    uint2v r13 = __builtin_amdgcn_permlane32_swap(pk[bb+1], pk[bb+3], false, false);
    out[kl].u = make_uint4(r02[0], r13[0], r02[1], r13[1]);
  }
}

// ---------------------------------------------------------------------------
// Flash attention, no-max softmax (exp2-space, scale*log2e folded into Q).
// Q,K flat (B*T, 1024) bf16; Vt (B,H,D,T) bf16; Y flat (B*T, 1024) bf16.
// 2 waves/block (128 thr), 64 q-rows/wave (2 groups of 32), grid 1024
// -> 4 independent blocks/CU (LDS 4x32KB=128KB). KV chunks of 64,
// double-buffered staging, counted vmcnt, raw s_barrier.
// ---------------------------------------------------------------------------
__global__ __launch_bounds__(128, 2) void attn_kernel(
    const ushort* __restrict__ Qg, const ushort* __restrict__ Kg,
    const ushort* __restrict__ Vtg, ushort* __restrict__ Yg)
{
  __shared__ uint4 smem[2048];            // 32 KB: 2 x (K 8KB + V 8KB)
  char* sK0 = (char*)smem;
  char* sV0 = (char*)smem + 8192;
  char* sK1 = (char*)smem + 16384;
  char* sV1 = (char*)smem + 24576;

  const int tid  = threadIdx.x;
  const int lane = tid & 63;
  const int w    = tid >> 6;              // 0..1
  const int ql   = lane & 31;
  const int hh   = lane >> 5;

  // XCD swizzle: all q-blocks of a head on one XCD (K/V L2-resident).
  int lin = blockIdx.y * 16 + blockIdx.x;       // 1024 blocks
  int xcd = lin & 7, j = lin >> 3;              // j in [0,128)
  const int bh  = (j >> 4) * 8 + xcd;
  const int qb  = j & 15;
  const int tq0 = qb * 128 + w * 64;
  const int b = bh >> 4, h = bh & 15;

  // Q fragments: qf[g][c] = Q[tq0+g*32+ql][16c+8hh+jj], flat layout
  U4 qf[2][4];
  #pragma unroll
  for (int g = 0; g < 2; g++){
    const char* qrow = (const char*)Qg + (long)(b*2048 + tq0 + g*32 + ql)*2048 + h*128 + hh*16;
    #pragma unroll
    for (int c = 0; c < 4; c++) qf[g][c].u = *(const uint4*)(qrow + c*32);
  }

  f32x16 y00 = {}, y01 = {}, y10 = {}, y11 = {};
  float ls0 = 0.f, ls1 = 0.f;

  const char* kbase = (const char*)Kg  + (long)b*2048*2048 + h*128;
  const char* vbase = (const char*)Vtg + (long)bh*64*4096;

  auto stage = [&](char* dK, char* dV, int kc){
    #pragma unroll
    for (int c2 = 0; c2 < 4; c2++){
      int o   = tid*16 + c2*2048;
      int row = o >> 7;
      int src = (o & 127) ^ ((row & 7) << 4);
      gload16(kbase + (long)(kc*64 + row)*2048 + src, dK + o);
      gload16(vbase + (long)row*4096 + (long)kc*128 + src, dV + o);
    }
  };

  auto sm = [&](f32x16& s, float& ls, uint (&pk)[8]){
    float ps = 0.f;
    #pragma unroll
    for (int r = 0; r < 16; r++){ s[r] = exp2a(s[r]); ps += s[r]; }
    ls += ps;
    #pragma unroll
    for (int i = 0; i < 8; i++) pk[i] = packbf(s[2*i], s[2*i+1]);
  };

  auto body = [&](int kc, char* cK, char* cV, char* nK, char* nV){
    if (kc < 31){
      stage(nK, nV, kc + 1);
      asm volatile("s_waitcnt vmcnt(8)" ::: "memory");
    } else {
      asm volatile("s_waitcnt vmcnt(0)" ::: "memory");
    }
    __builtin_amdgcn_s_barrier();

    // QK^T half 0 (kv 0-31)
    f32x16 s00 = {}, s10 = {};
    __builtin_amdgcn_s_setprio(1);
    #pragma unroll
    for (int ksd = 0; ksd < 4; ksd++){
      int kb = ksd*32 + hh*16;
      int r = ql;
      U4 a; a.u = *(const uint4*)(cK + r*128 + (kb ^ ((r & 7) << 4)));
      s00 = mfma32(a, qf[0][ksd], s00);
      s10 = mfma32(a, qf[1][ksd], s10);
    }
    __builtin_amdgcn_s_setprio(0);

    uint pk00[8], pk10[8];
    sm(s00, ls0, pk00); sm(s10, ls1, pk10);
    U4 f0[2], f1[2];
    mkfrag(pk00, f0); mkfrag(pk10, f1);

    // QK^T half 1 (kv 32-63)
    f32x16 s01 = {}, s11 = {};
    __builtin_amdgcn_s_setprio(1);
    #pragma unroll
    for (int ksd = 0; ksd < 4; ksd++){
      int kb = ksd*32 + hh*16;
      int r = 32 + ql;
      U4 a; a.u = *(const uint4*)(cK + r*128 + (kb ^ ((r & 7) << 4)));
      s01 = mfma32(a, qf[0][ksd], s01);
      s11 = mfma32(a, qf[1][ksd], s11);
    }

    // PV half 0 (MFMA) — overlaps sm of half 1 via scheduler
    #pragma unroll
    for (int kl = 0; kl < 2; kl++){
      int kvo = kl*32 + hh*16;
      U4 a0, a1;
      { int r = ql;      a0.u = *(const uint4*)(cV + r*128 + (kvo ^ ((r & 7) << 4))); }
      { int r = 32 + ql; a1.u = *(const uint4*)(cV + r*128 + (kvo ^ ((r & 7) << 4))); }
      y00 = mfma32(a0, f0[kl], y00);
      y01 = mfma32(a1, f0[kl], y01);
      y10 = mfma32(a0, f1[kl], y10);
      y11 = mfma32(a1, f1[kl], y11);
    }
    __builtin_amdgcn_s_setprio(0);

    uint pk01[8], pk11[8];
    sm(s01, ls0, pk01); sm(s11, ls1, pk11);
    mkfrag(pk01, f0); mkfrag(pk11, f1);

    // PV half 1
    __builtin_amdgcn_s_setprio(1);
    #pragma unroll
    for (int kl = 0; kl < 2; kl++){
      int kvo = 64 + kl*32 + hh*16;
      U4 a0, a1;
      { int r = ql;      a0.u = *(const uint4*)(cV + r*128 + (kvo ^ ((r & 7) << 4))); }
      { int r = 32 + ql; a1.u = *(const uint4*)(cV + r*128 + (kvo ^ ((r & 7) << 4))); }
      y00 = mfma32(a0, f0[kl], y00);
      y01 = mfma32(a1, f0[kl], y01);
      y10 = mfma32(a0, f1[kl], y10);
      y11 = mfma32(a1, f1[kl], y11);
    }
    __builtin_amdgcn_s_setprio(0);

    if (kc < 31){
      asm volatile("" ::: "memory");
      __builtin_amdgcn_s_barrier();
    }
  };

  stage(sK0, sV0, 0);
  for (int kc2 = 0; kc2 < 16; kc2++){
    body(2*kc2 + 0, sK0, sV0, sK1, sV1);
    body(2*kc2 + 1, sK1, sV1, sK0, sV0);
  }

  #pragma unroll
  for (int g = 0; g < 2; g++){
    f32x16& t0 = g ? y10 : y00;
    f32x16& t1 = g ? y11 : y01;
    float ls   = g ? ls1 : ls0;
    float lt   = ls + __shfl_xor(ls, 32);
    float inv  = 1.0f / lt;
    int tq = tq0 + g*32 + ql;
    ushort* yrow = Yg + ((long)b*2048 + tq)*1024 + h*64;
    #pragma unroll
    for (int qi = 0; qi < 4; qi++){
      ushort4 o0, o1;
      o0.x = f2bf(t0[qi*4+0]*inv); o0.y = f2bf(t0[qi*4+1]*inv);
      o0.z = f2bf(t0[qi*4+2]*inv); o0.w = f2bf(t0[qi*4+3]*inv);
      o1.x = f2bf(t1[qi*4+0]*inv); o1.y = f2bf(t1[qi*4+1]*inv);
      o1.z = f2bf(t1[qi*4+2]*inv); o1.w = f2bf(t1[qi*4+3]*inv);
      *(ushort4*)(yrow + qi*8 + hh*4)      = o0;
      *(ushort4*)(yrow + 32 + qi*8 + hh*4) = o1;
    }
  }
}

// ---------------------------------------------------------------------------
__global__ void cast_x_kernel(const float* __restrict__ x, ushort* __restrict__ xh)
{
  int i = blockIdx.x*256 + threadIdx.x;
  float4 v = ((const float4*)x)[i];
  ushort4 h;
  h.x = f2bf(v.x); h.y = f2bf(v.y); h.z = f2bf(v.z); h.w = f2bf(v.w);
  ((ushort4*)xh)[i] = h;
}

// All 4 W (1024x1024 fp32) -> W^T bf16 (K-contiguous), grid (16,16,4).
__global__ void wsplit_kernel(const float* __restrict__ W0, const float* __restrict__ W1,
                              const float* __restrict__ W2, const float* __restrict__ W3,
                              ushort* __restrict__ outbase)
{
  __shared__ float tile[64][65];
  const int z = blockIdx.z;
  const float* W = (z == 0) ? W0 : (z == 1) ? W1 : (z == 2) ? W2 : W3;
  ushort* Th = outbase + (long)z * 1048576;
  const int tid = threadIdx.x;
  const int k0 = blockIdx.x * 64;
  const int n0 = blockIdx.y * 64;
  #pragma unroll
  for (int c = 0; c < 4; c++){
    int idx = tid + 256*c;
    int r = idx >> 4, c4 = idx & 15;
    float4 v = *(const float4*)&W[(long)(k0 + r)*1024 + n0 + c4*4];
    tile[r][c4*4+0] = v.x; tile[r][c4*4+1] = v.y;
    tile[r][c4*4+2] = v.z; tile[r][c4*4+3] = v.w;
  }
  __syncthreads();
  #pragma unroll
  for (int c = 0; c < 4; c++){
    int idx = tid + 256*c;
    int nr = idx >> 4, k4 = idx & 15;
    ushort4 hh;
    hh.x = f2bf(tile[k4*4+0][nr]); hh.y = f2bf(tile[k4*4+1][nr]);
    hh.z = f2bf(tile[k4*4+2][nr]); hh.w = f2bf(tile[k4*4+3][nr]);
    *(ushort4*)&Th[(long)(n0 + nr)*1024 + k0 + k4*4] = hh;
  }
}

// ---------------------------------------------------------------------------
extern "C" void kernel_launch(void* const* d_in, const int* in_sizes, int n_in,
                              void* d_out, int out_size, void* d_ws, size_t ws_size,
                              hipStream_t stream)
{
  const float* x  = (const float*)d_in[0];
  const float* Wq = (const float*)d_in[1];
  const float* bq = (const float*)d_in[2];
  const float* Wk = (const float*)d_in[3];
  const float* bk = (const float*)d_in[4];
  const float* Wv = (const float*)d_in[5];
  const float* bv = (const float*)d_in[6];
  const float* Wp = (const float*)d_in[7];
  const float* bp = (const float*)d_in[8];

  char* ws = (char*)d_ws;
  const size_t SZ_X = 16777216; // 8192*1024*2 bytes
  const size_t SZ_W = 2097152;  // 1024*1024*2 bytes
  ushort* xh  = (ushort*)(ws);
  ushort* wqh = (ushort*)(ws + SZ_X);                 // wq,wk,wv,wp contiguous
  ushort* wph = (ushort*)(ws + SZ_X + 3*SZ_W);
  ushort* Qb  = (ushort*)(ws + SZ_X + 4*SZ_W);
  ushort* Kb  = (ushort*)(ws + 2*SZ_X + 4*SZ_W);
  ushort* Vtb = (ushort*)(ws + 3*SZ_X + 4*SZ_W);
  ushort* Yb  = (ushort*)(ws + 4*SZ_X + 4*SZ_W);

  cast_x_kernel<<<8192, 256, 0, stream>>>(x, xh);
  wsplit_kernel<<<dim3(16,16,4), 256, 0, stream>>>(Wq, Wk, Wv, Wp, wqh);

  // Q folds in softmax scale AND log2(e): 0.125 * 1.44269504
  gemm_qkv<<<dim3(64,24), 256, 0, stream>>>(xh, wqh, bq, bk, bv,
                                            Qb, Kb, Vtb, 0.18033688f);

  attn_kernel<<<dim3(16,64), 128, 0, stream>>>(Qb, Kb, Vtb, Yb);

  gemm_out<<<dim3(64,8), 256, 0, stream>>>(Yb, wph, bp, (float*)d_out);
}